// Round 4
// baseline (212.292 us; speedup 1.0000x reference)
//
#include <hip/hip_runtime.h>

// PatchEmbeder v5. v4's split showed all our kernels < 46 us; harness fills
// (310 MB @ 6.5 TB/s, 81% peak) dominate the top-5 and are not controllable.
// s1+s2 ~= 70-80 us vs ~27 us traffic floor. v5 attacks the visible slack:
//  - s2: SWAPPED MFMA OPERANDS (A=w3t frag, B=H frag) -> D[m=col][n=row]:
//    each lane holds 4 consecutive cols of one row -> f32x4 stores (4x fewer
//    store insts on the 77.5 MB output stream, the biggest single stream).
//    Operand fragments are bit-identical to v4's loads; only arg order and
//    the epilogue layout change.
//  - posb table dropped: s2 reads raw pos + folded bias vector bf[768]
//    (bf = b3 + (b1@W2+b2)@W3, computed once in prep — v4's prep2 recomputed
//    that fold 196x per column).
//  - preps merged into ONE kernel (4 independent regions, exact 771 blocks).
//  - s1 phase-2 reduce parallelized across all 4 waves (was wave-0-only).
// W1@W2 collapsed to W12 [768x64] (exact: no nonlinearity between them).

#define BATCH 128
#define CH    3
#define NP    196
#define PIX   256          // 16*16
#define K1    768          // CH*PIX
#define NH    64           // collapsed hidden width (W12 cols)
#define EMB   768
#define NROW  (BATCH * NP) // 25088 patch rows

typedef __bf16 bf16x8 __attribute__((ext_vector_type(8)));
typedef __bf16 bf16x4 __attribute__((ext_vector_type(4)));
typedef float  f32x4  __attribute__((ext_vector_type(4)));

// workspace byte offsets (16B aligned)
#define W12T_OFF 0                       // [64][768] bf16 = 98304
#define W3T_OFF  98304                   // [768][64] bf16 = 98304
#define BF_OFF   196608                  // [768] f32 = 3072
#define H_OFF    199680                  // [25088][64] bf16 = 3211264 -> ~3.4MB

// ---------------------------------------------------------------------------
// prep (single kernel, 4 independent regions, grid exactly 771*256 = 197376):
//  R0: w12t[n][k] = (W1@W2)^T bf16            (49152 threads, 32-FMA dot)
//  R1: bf[c] = b3[c] + (b1@W2 + b2) @ W3[:,c] (768 threads, ~2k FMA, cached)
//  R2: w3t[col][kk] = W3[kk][col] bf16        (49152 threads)
//  R3: out[b][0][c] = cls[c] + pos[0][c]      (98304 threads)
// ---------------------------------------------------------------------------
__global__ __launch_bounds__(256) void patchembed_prep(
    const float* __restrict__ W1, const float* __restrict__ W2,
    const float* __restrict__ b1, const float* __restrict__ b2,
    const float* __restrict__ W3, const float* __restrict__ b3,
    const float* __restrict__ cls, const float* __restrict__ pos,
    __bf16* __restrict__ w12t, __bf16* __restrict__ w3t,
    float* __restrict__ bf, float* __restrict__ out)
{
    const int i = blockIdx.x * 256 + threadIdx.x;
    const int T0 = NH * K1;            // 49152
    const int T1 = T0 + EMB;           // 49920
    const int T2 = T1 + EMB * NH;      // 99072
    // T3 = T2 + BATCH*EMB = 197376 == gridDim*256 (no tail check needed)

    if (i < T0) {                      // w12t[n][k] = sum_j W1[k][j] W2[j][n]
        const int n = i / K1, k = i - n * K1;
        float s = 0.f;
        #pragma unroll
        for (int j = 0; j < 32; ++j) s += W1[k * 32 + j] * W2[j * NH + n];
        w12t[i] = (__bf16)s;
    } else if (i < T1) {               // folded bias vector
        const int c = i - T0;
        float s = b3[c];
        for (int n = 0; n < NH; ++n) {
            float t = b2[n];
            #pragma unroll
            for (int j = 0; j < 32; ++j) t += b1[j] * W2[j * NH + n];
            s += t * W3[n * EMB + c];
        }
        bf[c] = s;
    } else if (i < T2) {               // w3t[col][kk] = W3[kk][col]
        const int j = i - T1;
        const int col = j >> 6, kk = j & 63;
        w3t[j] = (__bf16)W3[kk * EMB + col];
    } else {                           // cls rows of output
        const int j = i - T2;
        const int b = j / EMB, c = j - b * EMB;
        out[b * (197 * EMB) + c] = cls[c] + pos[c];
    }
}

// ---------------------------------------------------------------------------
// s1: stage-1 mm (x @ W12) -> H bf16. 16 rows/block, 4 waves, K-split 4-way
// (wave wv does ksteps [wv*6, wv*6+6)), f32 partials -> LDS; phase 2 reduce
// split across ALL 4 waves: thread (wv,l15,q) -> row l15, cols wv*16+q*4..+3.
// MFMA 16x16x32 bf16 layouts (verified m89/m120):
//   A: m = lane&15, k = (lane>>4)*8 + j
//   B: n = lane&15, k = (lane>>4)*8 + j
//   C: n(col idx) = lane&15, m(row idx) = (lane>>4)*4 + reg
// ---------------------------------------------------------------------------
__global__ __launch_bounds__(256) void patchembed_s1(
    const float* __restrict__ X,      // [B][C][P][256] fp32
    const __bf16* __restrict__ w12t,  // [64][768]
    __bf16* __restrict__ H)           // [25088][64]
{
    __shared__ __align__(16) float h1p[4][16][68];  // 17408 B

    const int tid  = threadIdx.x;
    const int wv   = tid >> 6;
    const int lane = tid & 63;
    const int l15  = lane & 15;
    const int q    = lane >> 4;
    const int r0   = blockIdx.x * 16;

    // ---------------- phase 1: partial H over K=192 per wave
    {
        const int xrow = r0 + l15;
        const int b = xrow / NP, p = xrow - b * NP;
        const float* xb = X + ((b * CH) * NP + p) * PIX;
        const int kb0 = wv * 6;

        f32x4 acc0 = {0.f, 0.f, 0.f, 0.f};
        f32x4 acc1 = acc0, acc2 = acc0, acc3 = acc0;
        #pragma unroll
        for (int t = 0; t < 6; ++t) {
            const int kb = kb0 + t;
            const float* ptr = xb + (kb >> 3) * (NP * PIX) + (kb & 7) * 32 + q * 8;
            float4 u = *(const float4*)ptr;
            float4 v = *(const float4*)(ptr + 4);
            bf16x8 a;
            a[0] = (__bf16)u.x; a[1] = (__bf16)u.y;
            a[2] = (__bf16)u.z; a[3] = (__bf16)u.w;
            a[4] = (__bf16)v.x; a[5] = (__bf16)v.y;
            a[6] = (__bf16)v.z; a[7] = (__bf16)v.w;
            const __bf16* wb = w12t + kb * 32 + q * 8;
            bf16x8 f0 = *(const bf16x8*)(wb + l15 * K1);
            bf16x8 f1 = *(const bf16x8*)(wb + (16 + l15) * K1);
            bf16x8 f2 = *(const bf16x8*)(wb + (32 + l15) * K1);
            bf16x8 f3 = *(const bf16x8*)(wb + (48 + l15) * K1);
            acc0 = __builtin_amdgcn_mfma_f32_16x16x32_bf16(a, f0, acc0, 0, 0, 0);
            acc1 = __builtin_amdgcn_mfma_f32_16x16x32_bf16(a, f1, acc1, 0, 0, 0);
            acc2 = __builtin_amdgcn_mfma_f32_16x16x32_bf16(a, f2, acc2, 0, 0, 0);
            acc3 = __builtin_amdgcn_mfma_f32_16x16x32_bf16(a, f3, acc3, 0, 0, 0);
        }
        #pragma unroll
        for (int r = 0; r < 4; ++r) {
            h1p[wv][q * 4 + r][l15]      = acc0[r];
            h1p[wv][q * 4 + r][16 + l15] = acc1[r];
            h1p[wv][q * 4 + r][32 + l15] = acc2[r];
            h1p[wv][q * 4 + r][48 + l15] = acc3[r];
        }
    }
    __syncthreads();

    // ---------------- phase 2: all-wave reduce -> H bf16
    {
        const int c0 = wv * 16 + q * 4;
        f32x4 s = {0.f, 0.f, 0.f, 0.f};
        #pragma unroll
        for (int w = 0; w < 4; ++w)
            s += *(const f32x4*)&h1p[w][l15][c0];
        bf16x4 hv;
        #pragma unroll
        for (int j = 0; j < 4; ++j) hv[j] = (__bf16)s[j];
        *(bf16x4*)(H + (r0 + l15) * NH + c0) = hv;
    }
}

// ---------------------------------------------------------------------------
// s2: stage-2 mm (H @ W3) + pos + bf -> out. NO LDS, NO barriers.
// Wave owns 16 rows x 96 cols: wave_id = blk*4+wv; rt = wave_id>>3 (row tile),
// cs = wave_id&7 (col segment). 12544 waves (49/CU) -> TLP hides latency.
// SWAPPED OPERANDS: mfma(A=w3t frag, B=H frag) -> D[m=col][n=row]; lane
// (q,l15) holds out[r0+l15][colb + q*4 .. +3] -> one f32x4 store per tile.
// Fragments are identical to the unswapped version (A and B layouts both
// index by lane&15 / q*8) — only the intrinsic arg order + epilogue change.
// ---------------------------------------------------------------------------
__global__ __launch_bounds__(256) void patchembed_s2(
    const __bf16* __restrict__ H,     // [25088][64]
    const __bf16* __restrict__ w3t,   // [768][64]
    const float*  __restrict__ bf,    // [768] folded bias
    const float*  __restrict__ pos,   // [197][768] raw input
    float* __restrict__ out)          // [B][197][768]
{
    const int tid  = threadIdx.x;
    const int wv   = tid >> 6;
    const int lane = tid & 63;
    const int l15  = lane & 15;
    const int q    = lane >> 4;

    const int wave_id = blockIdx.x * 4 + wv;
    const int rt = wave_id >> 3;          // 0..1567
    const int cs = wave_id & 7;           // 0..7
    const int r0 = rt * 16;

    // H fragment (B operand): row = r0 + l15, k = q*8..
    const __bf16* hr = H + (r0 + l15) * NH;
    bf16x8 hb0 = *(const bf16x8*)(hr + q * 8);
    bf16x8 hb1 = *(const bf16x8*)(hr + 32 + q * 8);

    // this lane's single output row
    const int row = r0 + l15;
    const int b = row / NP, p = row - b * NP;
    float* orow = out + (b * 197 + p + 1) * EMB;
    const float* prow = pos + (p + 1) * EMB;

    #pragma unroll
    for (int t = 0; t < 6; ++t) {
        const int colb = cs * 96 + t * 16;
        // w3t fragment (A operand): col-in-tile = l15, k = q*8..
        const __bf16* wr = w3t + (colb + l15) * NH;
        bf16x8 wa0 = *(const bf16x8*)(wr + q * 8);
        bf16x8 wa1 = *(const bf16x8*)(wr + 32 + q * 8);
        f32x4 z = {0.f, 0.f, 0.f, 0.f};
        f32x4 c = __builtin_amdgcn_mfma_f32_16x16x32_bf16(wa0, hb0, z, 0, 0, 0);
        c       = __builtin_amdgcn_mfma_f32_16x16x32_bf16(wa1, hb1, c, 0, 0, 0);
        const int c4 = colb + q * 4;
        f32x4 pv = *(const f32x4*)(prow + c4);
        f32x4 bv = *(const f32x4*)(bf + c4);
        *(f32x4*)(orow + c4) = c + pv + bv;
    }
}

extern "C" void kernel_launch(void* const* d_in, const int* in_sizes, int n_in,
                              void* d_out, int out_size, void* d_ws, size_t ws_size,
                              hipStream_t stream)
{
    const float* X   = (const float*)d_in[0];
    const float* W1  = (const float*)d_in[1];
    const float* b1  = (const float*)d_in[2];
    const float* W2  = (const float*)d_in[3];
    const float* b2  = (const float*)d_in[4];
    const float* W3  = (const float*)d_in[5];
    const float* b3  = (const float*)d_in[6];
    const float* cls = (const float*)d_in[7];
    const float* pos = (const float*)d_in[8];
    float* out = (float*)d_out;

    char* ws = (char*)d_ws;
    __bf16* w12t = (__bf16*)(ws + W12T_OFF);
    __bf16* w3t  = (__bf16*)(ws + W3T_OFF);
    float*  bf   = (float*)(ws + BF_OFF);
    __bf16* H    = (__bf16*)(ws + H_OFF);

    patchembed_prep<<<771, 256, 0, stream>>>(W1, W2, b1, b2, W3, b3, cls, pos,
                                             w12t, w3t, bf, out);
    patchembed_s1<<<NROW / 16, 256, 0, stream>>>(X, w12t, H);            // 1568
    patchembed_s2<<<NROW / 16 * 2, 256, 0, stream>>>(H, w3t, bf, pos, out); // 3136
}

// Round 5
// 208.931 us; speedup vs baseline: 1.0161x; 1.0161x over previous
//
#include <hip/hip_runtime.h>

// PatchEmbeder v6. v5 data: top controllable dispatch = s1 @ 45.6us, 925 GB/s,
// VGPR=44 — third straight round of compiler load-use serialization of
// global->VGPR loads. v6 rebuilds s1 on the proven global_load_lds staging
// path (async DMA to LDS, no VGPR round-trip, one vmcnt drain at the barrier):
//   - 48x global_load_lds(16B) stage the 16x768 f32 X tile (1KB chunk each)
//   - row stride padded to 772 floats -> conflict-free ds_read_b128
//   - wave wv computes n-tile wv over full K=768 (no partial-reduce LDS
//     round trip, no second barrier)
//   - swapped MFMA (A=w12t frag, B=X frag) -> lane holds 4 consecutive H
//     cols of one row -> single bf16x4 store
// prep and s2 are v5's verbatim (passed; s2/prep < 45.6us, below fills).
// W1@W2 collapsed to W12 [768x64] (exact); bf = b3+(b1@W2+b2)@W3 folded.

#define BATCH 128
#define CH    3
#define NP    196
#define PIX   256          // 16*16
#define K1    768          // CH*PIX
#define NH    64           // collapsed hidden width (W12 cols)
#define EMB   768
#define NROW  (BATCH * NP) // 25088 patch rows

typedef __bf16 bf16x8 __attribute__((ext_vector_type(8)));
typedef __bf16 bf16x4 __attribute__((ext_vector_type(4)));
typedef float  f32x4  __attribute__((ext_vector_type(4)));

// workspace byte offsets (16B aligned)
#define W12T_OFF 0                       // [64][768] bf16 = 98304
#define W3T_OFF  98304                   // [768][64] bf16 = 98304
#define BF_OFF   196608                  // [768] f32 = 3072
#define H_OFF    199680                  // [25088][64] bf16 = 3211264 -> ~3.4MB

// async global->LDS, 16B per lane (dst = wave-uniform base + lane*16)
#define GLOAD_LDS16(g, l)                                                  \
    __builtin_amdgcn_global_load_lds(                                      \
        (const __attribute__((address_space(1))) unsigned int*)(g),        \
        (__attribute__((address_space(3))) unsigned int*)(l), 16, 0, 0)

// ---------------------------------------------------------------------------
// prep (single kernel, 4 independent regions, grid exactly 771*256 = 197376):
//  R0: w12t[n][k] = (W1@W2)^T bf16            (49152 threads, 32-FMA dot)
//  R1: bf[c] = b3[c] + (b1@W2 + b2) @ W3[:,c] (768 threads)
//  R2: w3t[col][kk] = W3[kk][col] bf16        (49152 threads)
//  R3: out[b][0][c] = cls[c] + pos[0][c]      (98304 threads)
// ---------------------------------------------------------------------------
__global__ __launch_bounds__(256) void patchembed_prep(
    const float* __restrict__ W1, const float* __restrict__ W2,
    const float* __restrict__ b1, const float* __restrict__ b2,
    const float* __restrict__ W3, const float* __restrict__ b3,
    const float* __restrict__ cls, const float* __restrict__ pos,
    __bf16* __restrict__ w12t, __bf16* __restrict__ w3t,
    float* __restrict__ bf, float* __restrict__ out)
{
    const int i = blockIdx.x * 256 + threadIdx.x;
    const int T0 = NH * K1;            // 49152
    const int T1 = T0 + EMB;           // 49920
    const int T2 = T1 + EMB * NH;      // 99072
    // T3 = T2 + BATCH*EMB = 197376 == gridDim*256 (no tail check needed)

    if (i < T0) {                      // w12t[n][k] = sum_j W1[k][j] W2[j][n]
        const int n = i / K1, k = i - n * K1;
        float s = 0.f;
        #pragma unroll
        for (int j = 0; j < 32; ++j) s += W1[k * 32 + j] * W2[j * NH + n];
        w12t[i] = (__bf16)s;
    } else if (i < T1) {               // folded bias vector
        const int c = i - T0;
        float s = b3[c];
        for (int n = 0; n < NH; ++n) {
            float t = b2[n];
            #pragma unroll
            for (int j = 0; j < 32; ++j) t += b1[j] * W2[j * NH + n];
            s += t * W3[n * EMB + c];
        }
        bf[c] = s;
    } else if (i < T2) {               // w3t[col][kk] = W3[kk][col]
        const int j = i - T1;
        const int col = j >> 6, kk = j & 63;
        w3t[j] = (__bf16)W3[kk * EMB + col];
    } else {                           // cls rows of output
        const int j = i - T2;
        const int b = j / EMB, c = j - b * EMB;
        out[b * (197 * EMB) + c] = cls[c] + pos[c];
    }
}

// ---------------------------------------------------------------------------
// s1: stage-1 mm (x @ W12) -> H bf16. 16 rows/block, 4 waves.
//  stage: 48 chunks (16 rows x 3 ch, 1KB each) via global_load_lds, 12/wave,
//         all async; single vmcnt drain at __syncthreads.
//  compute: wave wv owns H cols [wv*16, wv*16+16); full K=768, 24 MFMA chain.
//  SWAPPED operands: mfma(A=w12t frag, B=X frag):
//   A: m=lane&15 (H col-in-tile), k=(lane>>4)*8+j  -> w12t[wv*16+l15][...]
//   B: n=lane&15 (patch row),     k=(lane>>4)*8+j  -> xs[l15][...] (cvt bf16)
//   C: n(col idx)=lane&15 -> patch row; m(row idx)=(lane>>4)*4+reg -> H col
//   => lane(q,l15) holds H[r0+l15][wv*16+q*4 .. +3] -> one bf16x4 store.
// LDS row stride 772 floats (3088B): lane bank-start = (4*l15+8*q)%32, same
// distribution as contiguous b128 reads -> conflict-free.
// ---------------------------------------------------------------------------
__global__ __launch_bounds__(256, 3) void patchembed_s1(
    const float* __restrict__ X,      // [B][C][P][256] fp32
    const __bf16* __restrict__ w12t,  // [64][768]
    __bf16* __restrict__ H)           // [25088][64]
{
    __shared__ __align__(16) float xs[16][772];   // 49408 B

    const int tid  = threadIdx.x;
    const int wv   = tid >> 6;
    const int lane = tid & 63;
    const int l15  = lane & 15;
    const int q    = lane >> 4;
    const int r0   = blockIdx.x * 16;

    const int b0 = r0 / NP;
    const int p0 = r0 - b0 * NP;

    // ---------------- stage: wave wv issues chunks [wv*12, wv*12+12)
    // chunk = c*16 + row  (c = chunk>>4, row = chunk&15)
    #pragma unroll
    for (int i = 0; i < 12; ++i) {
        const int chunk = wv * 12 + i;
        const int c   = chunk >> 4;
        const int row = chunk & 15;
        int p = p0 + row, b = b0;
        if (p >= NP) { p -= NP; b += 1; }
        const float* gp = X + (((b * CH) + c) * NP + p) * PIX + lane * 4;
        GLOAD_LDS16(gp, &xs[row][c * 256]);
    }
    __syncthreads();   // compiler emits s_waitcnt vmcnt(0) before s_barrier

    // ---------------- compute: full-K accumulate, one n-tile per wave
    const __bf16* wrow = w12t + (wv * 16 + l15) * K1;  // A: m = l15
    const float*  xrow = &xs[l15][0];                  // B: n = l15
    f32x4 acc = {0.f, 0.f, 0.f, 0.f};
    #pragma unroll
    for (int ks = 0; ks < 24; ++ks) {
        bf16x8 a = *(const bf16x8*)(wrow + ks * 32 + q * 8);
        const float* xp = xrow + ks * 32 + q * 8;
        f32x4 u = *(const f32x4*)xp;
        f32x4 v = *(const f32x4*)(xp + 4);
        bf16x8 xb;
        xb[0] = (__bf16)u[0]; xb[1] = (__bf16)u[1];
        xb[2] = (__bf16)u[2]; xb[3] = (__bf16)u[3];
        xb[4] = (__bf16)v[0]; xb[5] = (__bf16)v[1];
        xb[6] = (__bf16)v[2]; xb[7] = (__bf16)v[3];
        acc = __builtin_amdgcn_mfma_f32_16x16x32_bf16(a, xb, acc, 0, 0, 0);
    }
    bf16x4 hv;
    #pragma unroll
    for (int j = 0; j < 4; ++j) hv[j] = (__bf16)acc[j];
    *(bf16x4*)(H + (r0 + l15) * NH + wv * 16 + q * 4) = hv;
}

// ---------------------------------------------------------------------------
// s2: stage-2 mm (H @ W3) + pos + bf -> out. NO LDS, NO barriers.
// Wave owns 16 rows x 96 cols: wave_id = blk*4+wv; rt = wave_id>>3 (row tile),
// cs = wave_id&7 (col segment). 12544 waves (49/CU) -> TLP hides latency.
// SWAPPED OPERANDS: mfma(A=w3t frag, B=H frag) -> lane (q,l15) holds
// out[r0+l15][colb + q*4 .. +3] -> one f32x4 store per tile.
// ---------------------------------------------------------------------------
__global__ __launch_bounds__(256) void patchembed_s2(
    const __bf16* __restrict__ H,     // [25088][64]
    const __bf16* __restrict__ w3t,   // [768][64]
    const float*  __restrict__ bf,    // [768] folded bias
    const float*  __restrict__ pos,   // [197][768] raw input
    float* __restrict__ out)          // [B][197][768]
{
    const int tid  = threadIdx.x;
    const int wv   = tid >> 6;
    const int lane = tid & 63;
    const int l15  = lane & 15;
    const int q    = lane >> 4;

    const int wave_id = blockIdx.x * 4 + wv;
    const int rt = wave_id >> 3;          // 0..1567
    const int cs = wave_id & 7;           // 0..7
    const int r0 = rt * 16;

    // H fragment (B operand): row = r0 + l15, k = q*8..
    const __bf16* hr = H + (r0 + l15) * NH;
    bf16x8 hb0 = *(const bf16x8*)(hr + q * 8);
    bf16x8 hb1 = *(const bf16x8*)(hr + 32 + q * 8);

    // this lane's single output row
    const int row = r0 + l15;
    const int b = row / NP, p = row - b * NP;
    float* orow = out + (b * 197 + p + 1) * EMB;
    const float* prow = pos + (p + 1) * EMB;

    #pragma unroll
    for (int t = 0; t < 6; ++t) {
        const int colb = cs * 96 + t * 16;
        // w3t fragment (A operand): col-in-tile = l15, k = q*8..
        const __bf16* wr = w3t + (colb + l15) * NH;
        bf16x8 wa0 = *(const bf16x8*)(wr + q * 8);
        bf16x8 wa1 = *(const bf16x8*)(wr + 32 + q * 8);
        f32x4 z = {0.f, 0.f, 0.f, 0.f};
        f32x4 c = __builtin_amdgcn_mfma_f32_16x16x32_bf16(wa0, hb0, z, 0, 0, 0);
        c       = __builtin_amdgcn_mfma_f32_16x16x32_bf16(wa1, hb1, c, 0, 0, 0);
        const int c4 = colb + q * 4;
        f32x4 pv = *(const f32x4*)(prow + c4);
        f32x4 bv = *(const f32x4*)(bf + c4);
        *(f32x4*)(orow + c4) = c + pv + bv;
    }
}

extern "C" void kernel_launch(void* const* d_in, const int* in_sizes, int n_in,
                              void* d_out, int out_size, void* d_ws, size_t ws_size,
                              hipStream_t stream)
{
    const float* X   = (const float*)d_in[0];
    const float* W1  = (const float*)d_in[1];
    const float* b1  = (const float*)d_in[2];
    const float* W2  = (const float*)d_in[3];
    const float* b2  = (const float*)d_in[4];
    const float* W3  = (const float*)d_in[5];
    const float* b3  = (const float*)d_in[6];
    const float* cls = (const float*)d_in[7];
    const float* pos = (const float*)d_in[8];
    float* out = (float*)d_out;

    char* ws = (char*)d_ws;
    __bf16* w12t = (__bf16*)(ws + W12T_OFF);
    __bf16* w3t  = (__bf16*)(ws + W3T_OFF);
    float*  bf   = (float*)(ws + BF_OFF);
    __bf16* H    = (__bf16*)(ws + H_OFF);

    patchembed_prep<<<771, 256, 0, stream>>>(W1, W2, b1, b2, W3, b3, cls, pos,
                                             w12t, w3t, bf, out);
    patchembed_s1<<<NROW / 16, 256, 0, stream>>>(X, w12t, H);               // 1568
    patchembed_s2<<<NROW / 16 * 2, 256, 0, stream>>>(H, w3t, bf, pos, out); // 3136
}

// Round 7
// 193.989 us; speedup vs baseline: 1.0944x; 1.0770x over previous
//
#include <hip/hip_runtime.h>

// PatchEmbeder v7 (resubmit — round 6 was an infra failure, no HW data).
// v7 = v6 with ONE change (single-variable test): prep region R1
// (bf = b3 + (b1@W2+b2)@W3) was 768 threads (12 waves, zero TLP) each
// redundantly doing the full 64x32 b12 fold = ~2048 L2 loads/thread of
// exposed latency, serially AHEAD of s1/s2 in the stream and hidden below
// the 45us fill cutoff. Now block-cooperative: R1 spans exactly blocks
// 192..194 (T0/T1 on block boundaries -> the __syncthreads is block-uniform),
// so 64 threads compute b12[64] -> LDS (32 FMA each), barrier, then each
// thread does a 64-FMA coalesced dot. ~20x fewer loads on the prep critical
// path. s1/s2/other prep regions byte-identical to v6 (v6 data: all
// controllable dispatches < 45.1us; top-5 = harness fills 310MB @ 84-86%).
//
// Architecture (v6): W1@W2 collapsed to W12 [768x64] (exact, no nonlinearity);
//   s1: X tile (16x768 f32) -> LDS via 48x global_load_lds(16B) async DMA,
//       full-K=768 MFMA chain, swapped operands -> bf16x4 H store.
//   s2: H @ W3 + pos + bf -> out; no LDS/barriers, 12544 waves, TLP-hidden;
//       swapped operands -> f32x4 out stores.

#define BATCH 128
#define CH    3
#define NP    196
#define PIX   256          // 16*16
#define K1    768          // CH*PIX
#define NH    64           // collapsed hidden width (W12 cols)
#define EMB   768
#define NROW  (BATCH * NP) // 25088 patch rows

typedef __bf16 bf16x8 __attribute__((ext_vector_type(8)));
typedef __bf16 bf16x4 __attribute__((ext_vector_type(4)));
typedef float  f32x4  __attribute__((ext_vector_type(4)));

// workspace byte offsets (16B aligned)
#define W12T_OFF 0                       // [64][768] bf16 = 98304
#define W3T_OFF  98304                   // [768][64] bf16 = 98304
#define BF_OFF   196608                  // [768] f32 = 3072
#define H_OFF    199680                  // [25088][64] bf16 = 3211264 -> ~3.4MB

// async global->LDS, 16B per lane (dst = wave-uniform base + lane*16)
#define GLOAD_LDS16(g, l)                                                  \
    __builtin_amdgcn_global_load_lds(                                      \
        (const __attribute__((address_space(1))) unsigned int*)(g),        \
        (__attribute__((address_space(3))) unsigned int*)(l), 16, 0, 0)

// ---------------------------------------------------------------------------
// prep (single kernel, 4 independent regions, grid exactly 771*256 = 197376):
//  R0: w12t[n][k] = (W1@W2)^T bf16            (49152 threads, 32-FMA dot)
//  R1: bf[c] = b3[c] + (b1@W2 + b2) @ W3[:,c] (blocks 192..194, cooperative)
//  R2: w3t[col][kk] = W3[kk][col] bf16        (49152 threads)
//  R3: out[b][0][c] = cls[c] + pos[0][c]      (98304 threads)
// ---------------------------------------------------------------------------
__global__ __launch_bounds__(256) void patchembed_prep(
    const float* __restrict__ W1, const float* __restrict__ W2,
    const float* __restrict__ b1, const float* __restrict__ b2,
    const float* __restrict__ W3, const float* __restrict__ b3,
    const float* __restrict__ cls, const float* __restrict__ pos,
    __bf16* __restrict__ w12t, __bf16* __restrict__ w3t,
    float* __restrict__ bf, float* __restrict__ out)
{
    __shared__ float b12s[64];         // used only by R1 blocks (192..194)

    const int i = blockIdx.x * 256 + threadIdx.x;
    const int T0 = NH * K1;            // 49152 = 192*256 (R1 starts on a block boundary)
    const int T1 = T0 + EMB;           // 49920 = 195*256 (R1 ends on a block boundary)
    const int T2 = T1 + EMB * NH;      // 99072
    // T3 = T2 + BATCH*EMB = 197376 == gridDim*256 (no tail check needed)

    if (i < T0) {                      // w12t[n][k] = sum_j W1[k][j] W2[j][n]
        const int n = i / K1, k = i - n * K1;
        float s = 0.f;
        #pragma unroll
        for (int j = 0; j < 32; ++j) s += W1[k * 32 + j] * W2[j * NH + n];
        w12t[i] = (__bf16)s;
    } else if (i < T1) {               // folded bias vector, block-cooperative
        const int t = threadIdx.x;     // whole block is in this branch
        if (t < NH) {                  // b12[n] = b2[n] + b1 @ W2[:,n]
            float s = b2[t];
            #pragma unroll
            for (int j = 0; j < 32; ++j) s += b1[j] * W2[j * NH + t];
            b12s[t] = s;
        }
        __syncthreads();               // uniform: blocks 192..194 are pure-R1
        const int c = i - T0;          // 0..767
        float s = b3[c];
        #pragma unroll
        for (int n = 0; n < NH; ++n) s += b12s[n] * W3[n * EMB + c];
        bf[c] = s;
    } else if (i < T2) {               // w3t[col][kk] = W3[kk][col]
        const int j = i - T1;
        const int col = j >> 6, kk = j & 63;
        w3t[j] = (__bf16)W3[kk * EMB + col];
    } else {                           // cls rows of output
        const int j = i - T2;
        const int b = j / EMB, c = j - b * EMB;
        out[b * (197 * EMB) + c] = cls[c] + pos[c];
    }
}

// ---------------------------------------------------------------------------
// s1: stage-1 mm (x @ W12) -> H bf16. 16 rows/block, 4 waves. (v6 verbatim)
//  stage: 48 chunks (16 rows x 3 ch, 1KB each) via global_load_lds, 12/wave,
//         all async; single vmcnt drain at __syncthreads.
//  compute: wave wv owns H cols [wv*16, wv*16+16); full K=768, 24 MFMA chain.
//  SWAPPED operands: mfma(A=w12t frag, B=X frag) -> lane(q,l15) holds
//  H[r0+l15][wv*16+q*4 .. +3] -> one bf16x4 store.
// LDS row stride 772 floats (3088B): conflict-free b128 reads.
// ---------------------------------------------------------------------------
__global__ __launch_bounds__(256, 3) void patchembed_s1(
    const float* __restrict__ X,      // [B][C][P][256] fp32
    const __bf16* __restrict__ w12t,  // [64][768]
    __bf16* __restrict__ H)           // [25088][64]
{
    __shared__ __align__(16) float xs[16][772];   // 49408 B

    const int tid  = threadIdx.x;
    const int wv   = tid >> 6;
    const int lane = tid & 63;
    const int l15  = lane & 15;
    const int q    = lane >> 4;
    const int r0   = blockIdx.x * 16;

    const int b0 = r0 / NP;
    const int p0 = r0 - b0 * NP;

    // ---------------- stage: wave wv issues chunks [wv*12, wv*12+12)
    // chunk = c*16 + row  (c = chunk>>4, row = chunk&15)
    #pragma unroll
    for (int i = 0; i < 12; ++i) {
        const int chunk = wv * 12 + i;
        const int c   = chunk >> 4;
        const int row = chunk & 15;
        int p = p0 + row, b = b0;
        if (p >= NP) { p -= NP; b += 1; }
        const float* gp = X + (((b * CH) + c) * NP + p) * PIX + lane * 4;
        GLOAD_LDS16(gp, &xs[row][c * 256]);
    }
    __syncthreads();   // compiler emits s_waitcnt vmcnt(0) before s_barrier

    // ---------------- compute: full-K accumulate, one n-tile per wave
    const __bf16* wrow = w12t + (wv * 16 + l15) * K1;  // A: m = l15
    const float*  xrow = &xs[l15][0];                  // B: n = l15
    f32x4 acc = {0.f, 0.f, 0.f, 0.f};
    #pragma unroll
    for (int ks = 0; ks < 24; ++ks) {
        bf16x8 a = *(const bf16x8*)(wrow + ks * 32 + q * 8);
        const float* xp = xrow + ks * 32 + q * 8;
        f32x4 u = *(const f32x4*)xp;
        f32x4 v = *(const f32x4*)(xp + 4);
        bf16x8 xb;
        xb[0] = (__bf16)u[0]; xb[1] = (__bf16)u[1];
        xb[2] = (__bf16)u[2]; xb[3] = (__bf16)u[3];
        xb[4] = (__bf16)v[0]; xb[5] = (__bf16)v[1];
        xb[6] = (__bf16)v[2]; xb[7] = (__bf16)v[3];
        acc = __builtin_amdgcn_mfma_f32_16x16x32_bf16(a, xb, acc, 0, 0, 0);
    }
    bf16x4 hv;
    #pragma unroll
    for (int j = 0; j < 4; ++j) hv[j] = (__bf16)acc[j];
    *(bf16x4*)(H + (r0 + l15) * NH + wv * 16 + q * 4) = hv;
}

// ---------------------------------------------------------------------------
// s2: stage-2 mm (H @ W3) + pos + bf -> out. (v6 verbatim) NO LDS/barriers.
// Wave owns 16 rows x 96 cols; 12544 waves (49/CU) -> TLP hides latency.
// SWAPPED OPERANDS -> lane (q,l15) holds out[r0+l15][colb+q*4..+3] -> f32x4.
// ---------------------------------------------------------------------------
__global__ __launch_bounds__(256) void patchembed_s2(
    const __bf16* __restrict__ H,     // [25088][64]
    const __bf16* __restrict__ w3t,   // [768][64]
    const float*  __restrict__ bf,    // [768] folded bias
    const float*  __restrict__ pos,   // [197][768] raw input
    float* __restrict__ out)          // [B][197][768]
{
    const int tid  = threadIdx.x;
    const int wv   = tid >> 6;
    const int lane = tid & 63;
    const int l15  = lane & 15;
    const int q    = lane >> 4;

    const int wave_id = blockIdx.x * 4 + wv;
    const int rt = wave_id >> 3;          // 0..1567
    const int cs = wave_id & 7;           // 0..7
    const int r0 = rt * 16;

    // H fragment (B operand): row = r0 + l15, k = q*8..
    const __bf16* hr = H + (r0 + l15) * NH;
    bf16x8 hb0 = *(const bf16x8*)(hr + q * 8);
    bf16x8 hb1 = *(const bf16x8*)(hr + 32 + q * 8);

    // this lane's single output row
    const int row = r0 + l15;
    const int b = row / NP, p = row - b * NP;
    float* orow = out + (b * 197 + p + 1) * EMB;
    const float* prow = pos + (p + 1) * EMB;

    #pragma unroll
    for (int t = 0; t < 6; ++t) {
        const int colb = cs * 96 + t * 16;
        // w3t fragment (A operand): col-in-tile = l15, k = q*8..
        const __bf16* wr = w3t + (colb + l15) * NH;
        bf16x8 wa0 = *(const bf16x8*)(wr + q * 8);
        bf16x8 wa1 = *(const bf16x8*)(wr + 32 + q * 8);
        f32x4 z = {0.f, 0.f, 0.f, 0.f};
        f32x4 c = __builtin_amdgcn_mfma_f32_16x16x32_bf16(wa0, hb0, z, 0, 0, 0);
        c       = __builtin_amdgcn_mfma_f32_16x16x32_bf16(wa1, hb1, c, 0, 0, 0);
        const int c4 = colb + q * 4;
        f32x4 pv = *(const f32x4*)(prow + c4);
        f32x4 bv = *(const f32x4*)(bf + c4);
        *(f32x4*)(orow + c4) = c + pv + bv;
    }
}

extern "C" void kernel_launch(void* const* d_in, const int* in_sizes, int n_in,
                              void* d_out, int out_size, void* d_ws, size_t ws_size,
                              hipStream_t stream)
{
    const float* X   = (const float*)d_in[0];
    const float* W1  = (const float*)d_in[1];
    const float* b1  = (const float*)d_in[2];
    const float* W2  = (const float*)d_in[3];
    const float* b2  = (const float*)d_in[4];
    const float* W3  = (const float*)d_in[5];
    const float* b3  = (const float*)d_in[6];
    const float* cls = (const float*)d_in[7];
    const float* pos = (const float*)d_in[8];
    float* out = (float*)d_out;

    char* ws = (char*)d_ws;
    __bf16* w12t = (__bf16*)(ws + W12T_OFF);
    __bf16* w3t  = (__bf16*)(ws + W3T_OFF);
    float*  bf   = (float*)(ws + BF_OFF);
    __bf16* H    = (__bf16*)(ws + H_OFF);

    patchembed_prep<<<771, 256, 0, stream>>>(W1, W2, b1, b2, W3, b3, cls, pos,
                                             w12t, w3t, bf, out);
    patchembed_s1<<<NROW / 16, 256, 0, stream>>>(X, w12t, H);               // 1568
    patchembed_s2<<<NROW / 16 * 2, 256, 0, stream>>>(H, w3t, bf, pos, out); // 3136
}

// Round 8
// 192.410 us; speedup vs baseline: 1.1033x; 1.0082x over previous
//
#include <hip/hip_runtime.h>

// PatchEmbeder v8: fuse s1+s2 into ONE kernel, assembled only from the
// components that individually benched fast (v6/v7 data: every dispatch
// < 46us, below the harness-fill cutoff; totals flat within +-15us noise
// across 3-launch pipeline -> residual slack is launch gaps + H round-trip
// + latency tails). NOT a v3 revival: v3's slow parts are all replaced —
//   X staging:    global_load_lds async DMA (v3: VGPR loads, serialized)
//   s1 compute:   full-K=768 chain per wave (v3: K-split + f32 LDS reduce)
//   s2 epilogue:  swapped operands -> f32x4 stores (v3: 4x scalar scatter)
//   bias/pos:     pos + bf[768] vector (v3: 605KB posb table)
// Fusion adds only: h2s[16][72] bf16 LDS hop (2.3KB; s1-phase wave wv owns
// H cols [wv*16,+16), s2-phase frags need k=0..63 across waves) + one
// lgkm-only barrier. Deletes: 1 launch + device drain, 6.4MB H round-trip,
// 8x H re-read. LDS 51.7KB -> 3 blocks/CU.
// prep = v7 verbatim (passed; cooperative R1).
// W1@W2 collapsed to W12 [768x64] (exact); bf = b3+(b1@W2+b2)@W3 folded.

#define BATCH 128
#define CH    3
#define NP    196
#define PIX   256          // 16*16
#define K1    768          // CH*PIX
#define NH    64           // collapsed hidden width (W12 cols)
#define EMB   768
#define NROW  (BATCH * NP) // 25088 patch rows

typedef __bf16 bf16x8 __attribute__((ext_vector_type(8)));
typedef __bf16 bf16x4 __attribute__((ext_vector_type(4)));
typedef float  f32x4  __attribute__((ext_vector_type(4)));

// workspace byte offsets (16B aligned)
#define W12T_OFF 0                       // [64][768] bf16 = 98304
#define W3T_OFF  98304                   // [768][64] bf16 = 98304
#define BF_OFF   196608                  // [768] f32 = 3072 -> end 199680

// async global->LDS, 16B per lane (dst = wave-uniform base + lane*16)
#define GLOAD_LDS16(g, l)                                                  \
    __builtin_amdgcn_global_load_lds(                                      \
        (const __attribute__((address_space(1))) unsigned int*)(g),        \
        (__attribute__((address_space(3))) unsigned int*)(l), 16, 0, 0)

// ---------------------------------------------------------------------------
// prep (v7 verbatim; 4 independent regions, grid exactly 771*256 = 197376):
//  R0: w12t[n][k] = (W1@W2)^T bf16            (49152 threads, 32-FMA dot)
//  R1: bf[c] = b3[c] + (b1@W2 + b2) @ W3[:,c] (blocks 192..194, cooperative)
//  R2: w3t[col][kk] = W3[kk][col] bf16        (49152 threads)
//  R3: out[b][0][c] = cls[c] + pos[0][c]      (98304 threads)
// ---------------------------------------------------------------------------
__global__ __launch_bounds__(256) void patchembed_prep(
    const float* __restrict__ W1, const float* __restrict__ W2,
    const float* __restrict__ b1, const float* __restrict__ b2,
    const float* __restrict__ W3, const float* __restrict__ b3,
    const float* __restrict__ cls, const float* __restrict__ pos,
    __bf16* __restrict__ w12t, __bf16* __restrict__ w3t,
    float* __restrict__ bf, float* __restrict__ out)
{
    __shared__ float b12s[64];         // used only by R1 blocks (192..194)

    const int i = blockIdx.x * 256 + threadIdx.x;
    const int T0 = NH * K1;            // 49152 = 192*256 (block boundary)
    const int T1 = T0 + EMB;           // 49920 = 195*256 (block boundary)
    const int T2 = T1 + EMB * NH;      // 99072
    // T3 = T2 + BATCH*EMB = 197376 == gridDim*256 (no tail check needed)

    if (i < T0) {                      // w12t[n][k] = sum_j W1[k][j] W2[j][n]
        const int n = i / K1, k = i - n * K1;
        float s = 0.f;
        #pragma unroll
        for (int j = 0; j < 32; ++j) s += W1[k * 32 + j] * W2[j * NH + n];
        w12t[i] = (__bf16)s;
    } else if (i < T1) {               // folded bias vector, block-cooperative
        const int t = threadIdx.x;     // whole block is in this branch
        if (t < NH) {                  // b12[n] = b2[n] + b1 @ W2[:,n]
            float s = b2[t];
            #pragma unroll
            for (int j = 0; j < 32; ++j) s += b1[j] * W2[j * NH + t];
            b12s[t] = s;
        }
        __syncthreads();               // uniform: blocks 192..194 are pure-R1
        const int c = i - T0;          // 0..767
        float s = b3[c];
        #pragma unroll
        for (int n = 0; n < NH; ++n) s += b12s[n] * W3[n * EMB + c];
        bf[c] = s;
    } else if (i < T2) {               // w3t[col][kk] = W3[kk][col]
        const int j = i - T1;
        const int col = j >> 6, kk = j & 63;
        w3t[j] = (__bf16)W3[kk * EMB + col];
    } else {                           // cls rows of output
        const int j = i - T2;
        const int b = j / EMB, c = j - b * EMB;
        out[b * (197 * EMB) + c] = cls[c] + pos[c];
    }
}

// ---------------------------------------------------------------------------
// main (fused): 16 rows/block, 4 waves, 1568 blocks.
//  stage:  48x global_load_lds(16B) -> xs[16][772] (1KB (row,ch) chunks,
//          12/wave, async; one vmcnt drain at the first __syncthreads).
//  s1:     wave wv owns H cols [wv*16,+16); full K=768, 24-MFMA chain.
//          SWAPPED operands mfma(A=w12t frag, B=X frag) -> lane(q,l15)
//          holds H[r0+l15][wv*16+q*4..+3] -> bf16x4 to h2s (LDS, not global).
//  s2:     after lgkm-only barrier: wave wv owns out cols [wv*192,+192).
//          hb frags from h2s row l15; SWAPPED operands mfma(A=w3t, B=H) ->
//          lane(q,l15) holds out[r0+l15][colb+q*4..+3] -> f32x4 store
//          (+ pos f32x4 + bf f32x4).
// MFMA 16x16x32 bf16 layouts (verified m89/m120):
//   A: m = lane&15, k = (lane>>4)*8 + j
//   B: n = lane&15, k = (lane>>4)*8 + j
//   C: n(col idx) = lane&15, m(row idx) = (lane>>4)*4 + reg
// LDS: xs stride 772 f32 (conflict-free b128); h2s stride 72 bf16 (144B ->
// <=2-way on b64 writes / b128 reads; 2-way is free per m136). 51.7KB total.
// ---------------------------------------------------------------------------
__global__ __launch_bounds__(256, 3) void patchembed_main(
    const float* __restrict__ X,      // [B][C][P][256] fp32
    const __bf16* __restrict__ w12t,  // [64][768]
    const __bf16* __restrict__ w3t,   // [768][64]
    const float*  __restrict__ bf,    // [768] folded bias
    const float*  __restrict__ pos,   // [197][768] raw input
    float* __restrict__ out)          // [B][197][768]
{
    __shared__ __align__(16) float  xs[16][772];   // 49408 B
    __shared__ __align__(16) __bf16 h2s[16][72];   //  2304 B

    const int tid  = threadIdx.x;
    const int wv   = tid >> 6;
    const int lane = tid & 63;
    const int l15  = lane & 15;
    const int q    = lane >> 4;
    const int r0   = blockIdx.x * 16;

    const int b0 = r0 / NP;
    const int p0 = r0 - b0 * NP;

    // ---------------- stage: wave wv issues chunks [wv*12, wv*12+12)
    // chunk = c*16 + row  (c = chunk>>4, row = chunk&15)
    #pragma unroll
    for (int i = 0; i < 12; ++i) {
        const int chunk = wv * 12 + i;
        const int c   = chunk >> 4;
        const int row = chunk & 15;
        int p = p0 + row, b = b0;
        if (p >= NP) { p -= NP; b += 1; }
        const float* gp = X + (((b * CH) + c) * NP + p) * PIX + lane * 4;
        GLOAD_LDS16(gp, &xs[row][c * 256]);
    }
    __syncthreads();   // compiler emits s_waitcnt vmcnt(0) before s_barrier

    // ---------------- s1: full-K accumulate, one 16-col H tile per wave
    {
        const __bf16* wrow = w12t + (wv * 16 + l15) * K1;  // A: m = l15
        const float*  xrow = &xs[l15][0];                  // B: n = l15
        f32x4 acc = {0.f, 0.f, 0.f, 0.f};
        #pragma unroll
        for (int ks = 0; ks < 24; ++ks) {
            bf16x8 a = *(const bf16x8*)(wrow + ks * 32 + q * 8);
            const float* xp = xrow + ks * 32 + q * 8;
            f32x4 u = *(const f32x4*)xp;
            f32x4 v = *(const f32x4*)(xp + 4);
            bf16x8 xb;
            xb[0] = (__bf16)u[0]; xb[1] = (__bf16)u[1];
            xb[2] = (__bf16)u[2]; xb[3] = (__bf16)u[3];
            xb[4] = (__bf16)v[0]; xb[5] = (__bf16)v[1];
            xb[6] = (__bf16)v[2]; xb[7] = (__bf16)v[3];
            acc = __builtin_amdgcn_mfma_f32_16x16x32_bf16(a, xb, acc, 0, 0, 0);
        }
        bf16x4 hv;
        #pragma unroll
        for (int j = 0; j < 4; ++j) hv[j] = (__bf16)acc[j];
        *(bf16x4*)(&h2s[l15][wv * 16 + q * 4]) = hv;   // same values v6 sent to H
    }
    __syncthreads();   // lgkm-only drain (no vmem outstanding) — cheap

    // ---------------- s2: wave wv covers out cols [wv*192, wv*192+192)
    {
        bf16x8 hb0 = *(const bf16x8*)(&h2s[l15][q * 8]);
        bf16x8 hb1 = *(const bf16x8*)(&h2s[l15][32 + q * 8]);

        const int row = r0 + l15;
        const int b = row / NP, p = row - b * NP;
        float* orow = out + (b * 197 + p + 1) * EMB;
        const float* prow = pos + (p + 1) * EMB;

        #pragma unroll 4
        for (int t = 0; t < 12; ++t) {
            const int colb = wv * 192 + t * 16;
            const __bf16* wr = w3t + (colb + l15) * NH;   // A: m(col) = l15
            bf16x8 wa0 = *(const bf16x8*)(wr + q * 8);
            bf16x8 wa1 = *(const bf16x8*)(wr + 32 + q * 8);
            f32x4 z = {0.f, 0.f, 0.f, 0.f};
            f32x4 c = __builtin_amdgcn_mfma_f32_16x16x32_bf16(wa0, hb0, z, 0, 0, 0);
            c       = __builtin_amdgcn_mfma_f32_16x16x32_bf16(wa1, hb1, c, 0, 0, 0);
            const int c4 = colb + q * 4;
            f32x4 pv = *(const f32x4*)(prow + c4);
            f32x4 bv = *(const f32x4*)(bf + c4);
            *(f32x4*)(orow + c4) = c + pv + bv;
        }
    }
}

extern "C" void kernel_launch(void* const* d_in, const int* in_sizes, int n_in,
                              void* d_out, int out_size, void* d_ws, size_t ws_size,
                              hipStream_t stream)
{
    const float* X   = (const float*)d_in[0];
    const float* W1  = (const float*)d_in[1];
    const float* b1  = (const float*)d_in[2];
    const float* W2  = (const float*)d_in[3];
    const float* b2  = (const float*)d_in[4];
    const float* W3  = (const float*)d_in[5];
    const float* b3  = (const float*)d_in[6];
    const float* cls = (const float*)d_in[7];
    const float* pos = (const float*)d_in[8];
    float* out = (float*)d_out;

    char* ws = (char*)d_ws;
    __bf16* w12t = (__bf16*)(ws + W12T_OFF);
    __bf16* w3t  = (__bf16*)(ws + W3T_OFF);
    float*  bf   = (float*)(ws + BF_OFF);

    patchembed_prep<<<771, 256, 0, stream>>>(W1, W2, b1, b2, W3, b3, cls, pos,
                                             w12t, w3t, bf, out);
    patchembed_main<<<NROW / 16, 256, 0, stream>>>(X, w12t, w3t, bf, pos, out); // 1568
}

// Round 10
// 191.085 us; speedup vs baseline: 1.1110x; 1.0069x over previous
//
#include <hip/hip_runtime.h>

// PatchEmbeder v9 (resubmit — round 9 was an infra failure, no HW data; same
// mode as rounds 1/6, both of which passed on verbatim resubmit).
// v9 = v8 fused structure with ONE structural change: X staged in BF16 via
// reg round-trip (f32x4 load -> cvt -> ds_write bf16x4) instead of f32
// global_load_lds. Why: cross-arch latency model (v2b 74us@48%occ, v8
// 82us@25.7%occ, v5-s1 45.6us@32.7%occ, all VALU<8%/MFMA<2.3%/HBM<22%)
// says throughput ~ resident_waves in this latency-bound regime, and v8's
// 48KB f32 xs capped residency at 3 blocks/CU. bf16 tile = 24.8KB -> 27.1KB
// total LDS -> 5-6 blocks/CU (2x residency). Side win: s1 inner loop reads
// bf16x8 straight from LDS; the 8 cvts/kstep move off the MFMA critical path
// into the (independent, fire-and-forget) staging phase. Reg round-trip is
// safe for staging: load->cvt->write has no compute consumer, unlike the
// v2b/v3 load->MFMA chains the compiler serialized.
// Numerics identical to v8 (X was already bf16-rounded in reg before MFMA).
// prep = v7 verbatim. W1@W2 collapsed to W12 (exact); bf = b3+(b1@W2+b2)@W3.

#define BATCH 128
#define CH    3
#define NP    196
#define PIX   256          // 16*16
#define K1    768          // CH*PIX
#define NH    64           // collapsed hidden width (W12 cols)
#define EMB   768
#define NROW  (BATCH * NP) // 25088 patch rows
#define XSTR  776          // bf16 row stride: 1552B, 16B-aligned, bank-minimal

typedef __bf16 bf16x8 __attribute__((ext_vector_type(8)));
typedef __bf16 bf16x4 __attribute__((ext_vector_type(4)));
typedef float  f32x4  __attribute__((ext_vector_type(4)));

// workspace byte offsets (16B aligned)
#define W12T_OFF 0                       // [64][768] bf16 = 98304
#define W3T_OFF  98304                   // [768][64] bf16 = 98304
#define BF_OFF   196608                  // [768] f32 = 3072 -> end 199680

// ---------------------------------------------------------------------------
// prep (v7 verbatim; 4 independent regions, grid exactly 771*256 = 197376):
//  R0: w12t[n][k] = (W1@W2)^T bf16            (49152 threads, 32-FMA dot)
//  R1: bf[c] = b3[c] + (b1@W2 + b2) @ W3[:,c] (blocks 192..194, cooperative)
//  R2: w3t[col][kk] = W3[kk][col] bf16        (49152 threads)
//  R3: out[b][0][c] = cls[c] + pos[0][c]      (98304 threads)
// ---------------------------------------------------------------------------
__global__ __launch_bounds__(256) void patchembed_prep(
    const float* __restrict__ W1, const float* __restrict__ W2,
    const float* __restrict__ b1, const float* __restrict__ b2,
    const float* __restrict__ W3, const float* __restrict__ b3,
    const float* __restrict__ cls, const float* __restrict__ pos,
    __bf16* __restrict__ w12t, __bf16* __restrict__ w3t,
    float* __restrict__ bf, float* __restrict__ out)
{
    __shared__ float b12s[64];         // used only by R1 blocks (192..194)

    const int i = blockIdx.x * 256 + threadIdx.x;
    const int T0 = NH * K1;            // 49152 = 192*256 (block boundary)
    const int T1 = T0 + EMB;           // 49920 = 195*256 (block boundary)
    const int T2 = T1 + EMB * NH;      // 99072
    // T3 = T2 + BATCH*EMB = 197376 == gridDim*256 (no tail check needed)

    if (i < T0) {                      // w12t[n][k] = sum_j W1[k][j] W2[j][n]
        const int n = i / K1, k = i - n * K1;
        float s = 0.f;
        #pragma unroll
        for (int j = 0; j < 32; ++j) s += W1[k * 32 + j] * W2[j * NH + n];
        w12t[i] = (__bf16)s;
    } else if (i < T1) {               // folded bias vector, block-cooperative
        const int t = threadIdx.x;     // whole block is in this branch
        if (t < NH) {                  // b12[n] = b2[n] + b1 @ W2[:,n]
            float s = b2[t];
            #pragma unroll
            for (int j = 0; j < 32; ++j) s += b1[j] * W2[j * NH + t];
            b12s[t] = s;
        }
        __syncthreads();               // uniform: blocks 192..194 are pure-R1
        const int c = i - T0;          // 0..767
        float s = b3[c];
        #pragma unroll
        for (int n = 0; n < NH; ++n) s += b12s[n] * W3[n * EMB + c];
        bf[c] = s;
    } else if (i < T2) {               // w3t[col][kk] = W3[kk][col]
        const int j = i - T1;
        const int col = j >> 6, kk = j & 63;
        w3t[j] = (__bf16)W3[kk * EMB + col];
    } else {                           // cls rows of output
        const int j = i - T2;
        const int b = j / EMB, c = j - b * EMB;
        out[b * (197 * EMB) + c] = cls[c] + pos[c];
    }
}

// ---------------------------------------------------------------------------
// main (fused): 16 rows/block, 4 waves, 1568 blocks. LDS 27.1KB -> 5-6 bl/CU.
//  stage:  48 chunks (16 rows x 3 ch, 1KB f32 each): per chunk each lane
//          loads f32x4, cvts to bf16x4, ds_writes 8B -> xs_b[16][776] bf16.
//          Independent ops, no consumer -> TLP hides them at 20-24 waves/CU.
//  s1:     wave wv owns H cols [wv*16,+16); full K=768, 24-MFMA chain; B-frag
//          = ds_read bf16x8 (no cvt on critical path). SWAPPED operands
//          mfma(A=w12t, B=X) -> lane(q,l15) holds H[r0+l15][wv*16+q*4..+3]
//          -> bf16x4 to h2s (LDS hop).
//  s2:     after barrier: wave wv owns out cols [wv*192,+192); hb frags from
//          h2s row l15; SWAPPED operands -> f32x4 stores (+pos/+bf f32x4).
// MFMA 16x16x32 bf16 layouts (verified m89/m120):
//   A: m = lane&15, k = (lane>>4)*8 + j
//   B: n = lane&15, k = (lane>>4)*8 + j
//   C: n(col idx) = lane&15, m(row idx) = (lane>>4)*4 + reg
// Banks: xs_b stride 776 bf16 (1552B): b128 reads land exactly-minimal
// 8 words/bank; b64 writes 2-way (free, m136). h2s stride 72 (144B): <=2-way.
// ---------------------------------------------------------------------------
__global__ __launch_bounds__(256, 5) void patchembed_main(
    const float* __restrict__ X,      // [B][C][P][256] fp32
    const __bf16* __restrict__ w12t,  // [64][768]
    const __bf16* __restrict__ w3t,   // [768][64]
    const float*  __restrict__ bf,    // [768] folded bias
    const float*  __restrict__ pos,   // [197][768] raw input
    float* __restrict__ out)          // [B][197][768]
{
    __shared__ __align__(16) __bf16 xs_b[16][XSTR];  // 24832 B
    __shared__ __align__(16) __bf16 h2s[16][72];     //  2304 B

    const int tid  = threadIdx.x;
    const int wv   = tid >> 6;
    const int lane = tid & 63;
    const int l15  = lane & 15;
    const int q    = lane >> 4;
    const int r0   = blockIdx.x * 16;

    const int b0 = r0 / NP;
    const int p0 = r0 - b0 * NP;

    // ---------------- stage: wave wv handles chunks [wv*12, wv*12+12)
    // chunk = c*16 + row  (c = chunk>>4, row = chunk&15); 1KB f32 -> 512B bf16
    #pragma unroll
    for (int i = 0; i < 12; ++i) {
        const int chunk = wv * 12 + i;
        const int c   = chunk >> 4;
        const int row = chunk & 15;
        int p = p0 + row, b = b0;
        if (p >= NP) { p -= NP; b += 1; }
        f32x4 u = *(const f32x4*)(X + (((b * CH) + c) * NP + p) * PIX + lane * 4);
        bf16x4 v;
        v[0] = (__bf16)u[0]; v[1] = (__bf16)u[1];
        v[2] = (__bf16)u[2]; v[3] = (__bf16)u[3];
        *(bf16x4*)(&xs_b[row][c * 256 + lane * 4]) = v;
    }
    __syncthreads();

    // ---------------- s1: full-K accumulate, one 16-col H tile per wave
    {
        const __bf16* wrow = w12t + (wv * 16 + l15) * K1;  // A: m = l15
        const __bf16* xrow = &xs_b[l15][0];                // B: n = l15
        f32x4 acc = {0.f, 0.f, 0.f, 0.f};
        #pragma unroll
        for (int ks = 0; ks < 24; ++ks) {
            bf16x8 a  = *(const bf16x8*)(wrow + ks * 32 + q * 8);
            bf16x8 xb = *(const bf16x8*)(xrow + ks * 32 + q * 8);  // LDS b128
            acc = __builtin_amdgcn_mfma_f32_16x16x32_bf16(a, xb, acc, 0, 0, 0);
        }
        bf16x4 hv;
        #pragma unroll
        for (int j = 0; j < 4; ++j) hv[j] = (__bf16)acc[j];
        *(bf16x4*)(&h2s[l15][wv * 16 + q * 4]) = hv;
    }
    __syncthreads();   // lgkm-only drain — cheap

    // ---------------- s2: wave wv covers out cols [wv*192, wv*192+192)
    {
        bf16x8 hb0 = *(const bf16x8*)(&h2s[l15][q * 8]);
        bf16x8 hb1 = *(const bf16x8*)(&h2s[l15][32 + q * 8]);

        const int row = r0 + l15;
        const int b = row / NP, p = row - b * NP;
        float* orow = out + (b * 197 + p + 1) * EMB;
        const float* prow = pos + (p + 1) * EMB;

        #pragma unroll 4
        for (int t = 0; t < 12; ++t) {
            const int colb = wv * 192 + t * 16;
            const __bf16* wr = w3t + (colb + l15) * NH;   // A: m(col) = l15
            bf16x8 wa0 = *(const bf16x8*)(wr + q * 8);
            bf16x8 wa1 = *(const bf16x8*)(wr + 32 + q * 8);
            f32x4 z = {0.f, 0.f, 0.f, 0.f};
            f32x4 c = __builtin_amdgcn_mfma_f32_16x16x32_bf16(wa0, hb0, z, 0, 0, 0);
            c       = __builtin_amdgcn_mfma_f32_16x16x32_bf16(wa1, hb1, c, 0, 0, 0);
            const int c4 = colb + q * 4;
            f32x4 pv = *(const f32x4*)(prow + c4);
            f32x4 bv = *(const f32x4*)(bf + c4);
            *(f32x4*)(orow + c4) = c + pv + bv;
        }
    }
}

extern "C" void kernel_launch(void* const* d_in, const int* in_sizes, int n_in,
                              void* d_out, int out_size, void* d_ws, size_t ws_size,
                              hipStream_t stream)
{
    const float* X   = (const float*)d_in[0];
    const float* W1  = (const float*)d_in[1];
    const float* b1  = (const float*)d_in[2];
    const float* W2  = (const float*)d_in[3];
    const float* b2  = (const float*)d_in[4];
    const float* W3  = (const float*)d_in[5];
    const float* b3  = (const float*)d_in[6];
    const float* cls = (const float*)d_in[7];
    const float* pos = (const float*)d_in[8];
    float* out = (float*)d_out;

    char* ws = (char*)d_ws;
    __bf16* w12t = (__bf16*)(ws + W12T_OFF);
    __bf16* w3t  = (__bf16*)(ws + W3T_OFF);
    float*  bf   = (float*)(ws + BF_OFF);

    patchembed_prep<<<771, 256, 0, stream>>>(W1, W2, b1, b2, W3, b3, cls, pos,
                                             w12t, w3t, bf, out);
    patchembed_main<<<NROW / 16, 256, 0, stream>>>(X, w12t, w3t, bf, pos, out); // 1568
}